// Round 17
// baseline (953.414 us; speedup 1.0000x reference)
//
#include <hip/hip_runtime.h>

#define G 4096
#define BSZ 2
#define NIN 8
#define HID 32
#define NLOG2E (-1.4426950408889634f)

typedef __attribute__((ext_vector_type(8))) short short8;
typedef __attribute__((ext_vector_type(4))) float floatx4;
typedef unsigned short ushort_t;
typedef unsigned int uint_t;

__device__ __forceinline__ float elu1(float v) {
    return v > 0.f ? v : (__expf(v) - 1.f);
}
__device__ __forceinline__ ushort_t f2bf(float f) {
    unsigned u = __float_as_uint(f);
    u += 0x7fffu + ((u >> 16) & 1u);
    return (ushort_t)(u >> 16);
}

// h = elu(x@W_infer+b); ssrc stored as E=exp2(ss*-log2e) (=exp(-ss));
// sdst linear pre-scaled by -log2e. hT bf16 [b][c][g] via LDS transpose.
// Zeroes BOTH layers' epilogue arrival counters each launch (R16 bug:
// k_setup1 has 256 threads, so 'tid < 512' left cnt[256..511] stale ->
// layer-2 epilogue never fired after the first launch).
__global__ __launch_bounds__(256) void k_setup1(
    const float* __restrict__ x, const float* __restrict__ W,
    const float* __restrict__ bias, const float* __restrict__ We,
    float* __restrict__ h0, ushort_t* __restrict__ hTb,
    float* __restrict__ ssrc, float* __restrict__ sdst,
    uint_t* __restrict__ cnt) {
    __shared__ __align__(16) ushort_t hs[HID][264];
    int tid = threadIdx.x;
    if (blockIdx.x == 0) {
        cnt[tid] = 0;          // layer-1 counters
        cnt[tid + 256] = 0;    // layer-2 counters
    }
    int t = blockIdx.x * 256 + tid;
    int b = t >> 12;
    int g0 = (blockIdx.x & 15) * 256;
    float xin[NIN];
    const float* xp = x + t * NIN;
#pragma unroll
    for (int k = 0; k < NIN; k++) xin[k] = xp[k];
    float ss = 0.f, sd = 0.f;
    float* hp = h0 + (size_t)t * HID;
#pragma unroll
    for (int o = 0; o < HID; o++) {
        float v = bias[o];
#pragma unroll
        for (int k = 0; k < NIN; k++) v += xin[k] * W[k * HID + o];
        v = elu1(v);
        hp[o] = v;
        hs[o][tid] = f2bf(v);
        ss += v * We[o];
        sd += v * We[HID + o];
    }
    ssrc[t] = exp2f(ss * NLOG2E);   // E_j = exp(-ss_j)
    sdst[t] = sd * NLOG2E;          // linear, consumer folds bias + exp2
    __syncthreads();
#pragma unroll
    for (int p = 0; p < 4; p++) {
        int row = p * 8 + (tid >> 5);
        int c = (tid & 31) * 8;
        short8 v8 = *(const short8*)&hs[row][c];
        *(short8*)(void*)&hTb[(size_t)(b * HID + row) * G + g0 + c] = v8;
    }
}

// Message-passing with FUSED EPILOGUE: grid 1024 = 256 gene-blocks x 4
// j-quarters (R12-best geometry, byte-identical main loop). After the
// partial write, the LAST of the 4 quarter-blocks (device-scope atomic
// arrival counter, threadfence release/acquire) runs the post phase
// in-block (R8-proven 512-thread 2-pass form): combines 4 partials +
// node/merge MLP (+BN+proj+hT for layer 1). Removes both k_post dispatches
// and their stream-boundary gaps. Winner self-resets its counter.
template <bool DO_BN>
__global__ __launch_bounds__(512, 2) void k_mp(
    const float* __restrict__ adj, const float* __restrict__ ssrc,
    const float* __restrict__ sdst, const ushort_t* __restrict__ hTb_in,
    const float* __restrict__ bep, float coef, float* __restrict__ pr,
    uint_t* __restrict__ cnt, const float* __restrict__ hin,
    const float* __restrict__ Wn, const float* __restrict__ bnb,
    const float* __restrict__ Wm, const float* __restrict__ bmb,
    const float* __restrict__ gamma, const float* __restrict__ beta,
    const float* __restrict__ We2, float* __restrict__ outp,
    ushort_t* __restrict__ hTb_out, float* __restrict__ s2s,
    float* __restrict__ s2d) {
    union SMem {
        struct {                                // compute phase (~24 KB)
            float ssm[BSZ][1024];
            uint_t abits[32][17];
            float red[6][64][9];
        } c;
        struct {                                // post phase (~35.8 KB)
            float rec[32][68];
            float rec2[32][68];
            ushort_t tb[BSZ][HID][16];
            float Wns[2048];
            float Wms[2048];
        } p;
    };
    __shared__ __align__(16) SMem sm;
    __shared__ int s_arr;

    int tid = threadIdx.x;              // 0..511
    int gblk = blockIdx.x >> 2, jh = blockIdx.x & 3;
    int g0 = gblk * 16, j0 = jh * 1024;
    int l = tid & 63, w = tid >> 6;     // wave 0..7
    int b = w >> 2, jq = w & 3;
    int m = l & 15, kg = l >> 4;

    // hTb prefetch first (longest dependency to first MFMA)
    int jstart = j0 + jq * 256;
    const ushort_t* hb0 = hTb_in + (size_t)(b * HID + m) * G + jstart + kg * 8;
    const ushort_t* hb1 = hb0 + (size_t)16 * G;
    short8 pb0[2], pb1[2];
#pragma unroll
    for (int d = 0; d < 2; d++) {
        pb0[d] = *(const short8*)(const void*)(hb0 + d * 32);
        pb1[d] = *(const short8*)(const void*)(hb1 + d * 32);
    }

    // stage ssm quarter (E values): 1 float4/thread
    {
        int bb = tid >> 8, j4 = tid & 255;
        *(float4*)&sm.c.ssm[bb][j4 * 4] = *(const float4*)&ssrc[bb * G + j0 + j4 * 4];
    }
    // stage adjacency bits: 2 passes x 4-deep batched loads, then pack
    {
        int r = tid >> 8, f4 = tid & 255;
        int word = f4 >> 3;
        int sh2 = (tid & 7) * 4;
        bool st = (tid & 7) == 0;
        float4 ld[4];
#pragma unroll
        for (int half = 0; half < 2; half++) {
#pragma unroll
            for (int q = 0; q < 4; q++)
                ld[q] = *(const float4*)&adj[(size_t)(g0 + (half * 4 + q) * 2 + r) * G +
                                             j0 + f4 * 4];
#pragma unroll
            for (int q = 0; q < 4; q++) {
                float4 v4 = ld[q];
                uint_t nib = (uint_t)(v4.x != 0.f) | ((uint_t)(v4.y != 0.f) << 1) |
                             ((uint_t)(v4.z != 0.f) << 2) | ((uint_t)(v4.w != 0.f) << 3);
                uint_t wd = nib << sh2;
                wd |= __shfl_xor(wd, 1);
                wd |= __shfl_xor(wd, 2);
                wd |= __shfl_xor(wd, 4);
                if (st) sm.c.abits[word][(half * 4 + q) * 2 + r] = wd;
            }
        }
    }

    float Dv = exp2f(sdst[b * G + g0 + m] + bep[0] * NLOG2E);  // exp(-(sd_i+b_e))
    const float wm1 = 1.f - coef;
    floatx4 c0 = {0.f, 0.f, 0.f, 0.f}, c1 = {0.f, 0.f, 0.f, 0.f};
    float es = 0.f;
    __syncthreads();

    const float* svp = &sm.c.ssm[b][jq * 256 + kg * 8];
    float4 sv0[2], sv1[2];
    uint_t bwr[2];
#pragma unroll
    for (int d = 0; d < 2; d++) {
        sv0[d] = *(const float4*)&svp[d * 32];
        sv1[d] = *(const float4*)&svp[d * 32 + 4];
        bwr[d] = sm.c.abits[jq * 8 + d][m];
    }

#pragma unroll
    for (int jc = 0; jc < 8; jc++) {
        int lc = jc & 1;
        short8 bf0 = pb0[lc], bf1 = pb1[lc];
        float4 s0 = sv0[lc], s1 = sv1[lc];
        uint_t bw = bwr[lc];
        if (jc + 2 < 8) {
            pb0[lc] = *(const short8*)(const void*)(hb0 + (jc + 2) * 32);
            pb1[lc] = *(const short8*)(const void*)(hb1 + (jc + 2) * 32);
            sv0[lc] = *(const float4*)&svp[(jc + 2) * 32];
            sv1[lc] = *(const float4*)&svp[(jc + 2) * 32 + 4];
            bwr[lc] = sm.c.abits[jq * 8 + jc + 2][m];
        }
        float ev[8] = {s0.x, s0.y, s0.z, s0.w, s1.x, s1.y, s1.z, s1.w};
        short8 af;
#pragma unroll
        for (int t8 = 0; t8 < 8; t8++) {
            float bitf = (float)((bw >> (kg * 8 + t8)) & 1u);
            float wgt = __builtin_fmaf(bitf, wm1, coef);  // bit?1:coef
            float ex = Dv * ev[t8];                       // = exp(-logit)
            float e = __builtin_amdgcn_rcpf(1.f + ex) * wgt;
            es += e;
            af[t8] = (short)(__float_as_uint(e) >> 16);   // bf16 by truncation
        }
        c0 = __builtin_amdgcn_mfma_f32_16x16x32_bf16(af, bf0, c0, 0, 0, 0);
        c1 = __builtin_amdgcn_mfma_f32_16x16x32_bf16(af, bf1, c1, 0, 0, 0);
    }

    // 4-way jq merge
    if (jq) {
        int widx = b * 3 + jq - 1;
#pragma unroll
        for (int r = 0; r < 4; r++) {
            sm.c.red[widx][l][r] = c0[r];
            sm.c.red[widx][l][4 + r] = c1[r];
        }
        sm.c.red[widx][l][8] = es;
    }
    __syncthreads();
    if (!jq) {
#pragma unroll
        for (int q = 0; q < 3; q++) {
            int widx = b * 3 + q;
#pragma unroll
            for (int r = 0; r < 4; r++) {
                c0[r] += sm.c.red[widx][l][r];
                c1[r] += sm.c.red[widx][l][4 + r];
            }
            es += sm.c.red[widx][l][8];
        }
        es += __shfl_xor(es, 16);
        es += __shfl_xor(es, 32);
        float* prb = pr + (size_t)blockIdx.x * 1056;
#pragma unroll
        for (int r = 0; r < 4; r++) {
            int gene = (l >> 4) * 4 + r;   // C/D: row=(l>>4)*4+reg, col=l&15
            int row = gene * 2 + b;
            prb[row * 32 + m] = c0[r];
            prb[row * 32 + 16 + m] = c1[r];
        }
        if (l < 16) prb[1024 + l * 2 + b] = es;
    }

    // ---- fused epilogue: last arriving quarter-block does the post ----
    __threadfence();                         // release pr to device scope
    __syncthreads();
    if (tid == 0) s_arr = (int)atomicAdd(&cnt[gblk], 1u);
    __syncthreads();
    if (s_arr != 3) return;                  // block-uniform
    __threadfence();                         // acquire: see peers' pr
    if (tid == 0) cnt[gblk] = 0;             // self-reset for next launch

    // stage weights (512 float4 each)
    ((float4*)sm.p.Wns)[tid] = ((const float4*)Wn)[tid];
    ((float4*)sm.p.Wms)[tid] = ((const float4*)Wm)[tid];

    int rl = tid >> 5, hh = tid & 31;
    const float* p0 = pr + (size_t)(gblk * 4) * 1056;
    float xv[2];
#pragma unroll
    for (int pp = 0; pp < 2; pp++) {
        int rr = rl + pp * 16;
        float rv = p0[rr * 32 + hh] + p0[1056 + rr * 32 + hh] +
                   p0[2112 + rr * 32 + hh] + p0[3168 + rr * 32 + hh];
        float esv = p0[1024 + rr] + p0[2080 + rr] + p0[3136 + rr] + p0[4192 + rr];
        int gene = rr >> 1, bb = rr & 1;
        xv[pp] = hin[((size_t)(bb * G + g0 + gene)) * HID + hh];
        sm.p.rec[rr][hh] = rv;
        sm.p.rec[rr][32 + hh] = xv[pp] * esv;
    }
    __syncthreads();

#pragma unroll
    for (int pp = 0; pp < 2; pp++) {
        int rr = rl + pp * 16, gene = rr >> 1, bb = rr & 1;
        float v = bnb[hh];
#pragma unroll
        for (int k4 = 0; k4 < 16; k4++) {
            float4 r4 = *(const float4*)&sm.p.rec[rr][k4 * 4];
            v += r4.x * sm.p.Wns[(k4 * 4 + 0) * HID + hh];
            v += r4.y * sm.p.Wns[(k4 * 4 + 1) * HID + hh];
            v += r4.z * sm.p.Wns[(k4 * 4 + 2) * HID + hh];
            v += r4.w * sm.p.Wns[(k4 * 4 + 3) * HID + hh];
        }
        v = elu1(v);
        sm.p.rec2[rr][hh] = v;
        sm.p.rec2[rr][32 + hh] = xv[pp];
        // row handled by one half-wave: lockstep makes rec2 visible w/o barrier
        float u = bmb[hh];
#pragma unroll
        for (int k4 = 0; k4 < 16; k4++) {
            float4 r4 = *(const float4*)&sm.p.rec2[rr][k4 * 4];
            u += r4.x * sm.p.Wms[(k4 * 4 + 0) * HID + hh];
            u += r4.y * sm.p.Wms[(k4 * 4 + 1) * HID + hh];
            u += r4.z * sm.p.Wms[(k4 * 4 + 2) * HID + hh];
            u += r4.w * sm.p.Wms[(k4 * 4 + 3) * HID + hh];
        }
        float h1v = elu1(u);
        if (!DO_BN) {
            outp[((size_t)(bb * G + g0 + gene)) * HID + hh] = h1v;
        } else {
            // wave holds gene's full 64 values (lanes 0-31: b=0, 32-63: b=1)
            float s = h1v, sq = h1v * h1v;
#pragma unroll
            for (int mm = 32; mm; mm >>= 1) {
                s += __shfl_xor(s, mm);
                sq += __shfl_xor(sq, mm);
            }
            float mu = s * (1.f / 64.f);
            float var = sq * (1.f / 64.f) - mu * mu;
            float rstd = rsqrtf(var + 1e-5f);
            float hn = (h1v - mu) * rstd * gamma[g0 + gene] + beta[g0 + gene];
            outp[((size_t)(bb * G + g0 + gene)) * HID + hh] = hn;
            sm.p.tb[bb][hh][gene] = f2bf(hn);
            float ps = hn * We2[hh], pd = hn * We2[HID + hh];
#pragma unroll
            for (int mm = 16; mm; mm >>= 1) {
                ps += __shfl_xor(ps, mm);
                pd += __shfl_xor(pd, mm);
            }
            if (hh == 0) {
                s2s[bb * G + g0 + gene] = exp2f(ps * NLOG2E);  // E for layer 2
                s2d[bb * G + g0 + gene] = pd * NLOG2E;         // linear
            }
        }
    }
    if (DO_BN) {
        __syncthreads();
        if (tid < 128) {
            int b2 = tid >> 6, c = (tid >> 1) & 31, half = tid & 1;
            short8 v8 = *(const short8*)&sm.p.tb[b2][c][half * 8];
            *(short8*)(void*)&hTb_out[(size_t)(b2 * HID + c) * G + g0 + half * 8] = v8;
        }
    }
}

extern "C" void kernel_launch(void* const* d_in, const int* in_sizes, int n_in,
                              void* d_out, int out_size, void* d_ws, size_t ws_size,
                              hipStream_t stream) {
    const float* x      = (const float*)d_in[0];
    const float* edges1 = (const float*)d_in[1];
    const float* edges2 = (const float*)d_in[2];
    const float* W_inf  = (const float*)d_in[3];
    const float* b_inf  = (const float*)d_in[4];
    const float* W_e1   = (const float*)d_in[5];
    const float* b_e1   = (const float*)d_in[6];
    const float* W_e2   = (const float*)d_in[7];
    const float* b_e2   = (const float*)d_in[8];
    const float* W_n1   = (const float*)d_in[9];
    const float* b_n1   = (const float*)d_in[10];
    const float* W_n2   = (const float*)d_in[11];
    const float* b_n2   = (const float*)d_in[12];
    const float* W_m1   = (const float*)d_in[13];
    const float* b_m1   = (const float*)d_in[14];
    const float* W_m2   = (const float*)d_in[15];
    const float* b_m2   = (const float*)d_in[16];
    const float* bn_g   = (const float*)d_in[17];
    const float* bn_b   = (const float*)d_in[18];
    float* out = (float*)d_out;

    float* ws = (float*)d_ws;
    float* h0   = ws;                           // 262144 floats
    float* h1n  = ws + 262144;                  // 262144
    float* s1s  = ws + 524288;                  // 8192
    float* s1d  = ws + 532480;                  // 8192
    float* s2s  = ws + 540672;                  // 8192
    float* s2d  = ws + 548864;                  // 8192
    ushort_t* hTb  = (ushort_t*)(ws + 557056);  // 262144 ushorts = 131072 floats
    ushort_t* hTb2 = (ushort_t*)(ws + 688128);  // 262144 ushorts
    float* pr = ws + 819200;                    // 1024*1056 = 1081344 floats
    uint_t* cnt = (uint_t*)(ws + 1900544);      // 512 uints (layer1: 0..255, layer2: 256..511)
    // total ~ 1900672 floats = 7.6 MB

    const float ALPHA = 0.005f, BETA = 5e-5f;

    k_setup1<<<32, 256, 0, stream>>>(x, W_inf, b_inf, W_e1, h0, hTb, s1s, s1d, cnt);
    k_mp<true><<<1024, 512, 0, stream>>>(
        edges1, s1s, s1d, hTb, b_e1, ALPHA, pr, cnt,
        h0, W_n1, b_n1, W_m1, b_m1, bn_g, bn_b, W_e2,
        h1n, hTb2, s2s, s2d);
    k_mp<false><<<1024, 512, 0, stream>>>(
        edges2, s2s, s2d, hTb2, b_e2, BETA, pr, cnt + 256,
        h1n, W_n2, b_n2, W_m2, b_m2, nullptr, nullptr, nullptr,
        out, nullptr, nullptr, nullptr);
}

// Round 19
// 218.081 us; speedup vs baseline: 4.3718x; 4.3718x over previous
//
#include <hip/hip_runtime.h>

#define G 4096
#define BSZ 2
#define NIN 8
#define HID 32
#define NLOG2E (-1.4426950408889634f)

typedef __attribute__((ext_vector_type(8))) short short8;
typedef __attribute__((ext_vector_type(4))) float floatx4;
typedef unsigned short ushort_t;
typedef unsigned int uint_t;

__device__ __forceinline__ float elu1(float v) {
    return v > 0.f ? v : (__expf(v) - 1.f);
}
__device__ __forceinline__ ushort_t f2bf(float f) {
    unsigned u = __float_as_uint(f);
    u += 0x7fffu + ((u >> 16) & 1u);
    return (ushort_t)(u >> 16);
}

// h = elu(x@W_infer+b); ssrc stored as E=exp2(ss*-log2e) (=exp(-ss));
// sdst linear pre-scaled by -log2e. hT bf16 [b][c][g] via LDS transpose.
__global__ __launch_bounds__(256) void k_setup1(
    const float* __restrict__ x, const float* __restrict__ W,
    const float* __restrict__ bias, const float* __restrict__ We,
    float* __restrict__ h0, ushort_t* __restrict__ hTb,
    float* __restrict__ ssrc, float* __restrict__ sdst) {
    __shared__ __align__(16) ushort_t hs[HID][264];
    int tid = threadIdx.x;
    int t = blockIdx.x * 256 + tid;
    int b = t >> 12;
    int g0 = (blockIdx.x & 15) * 256;
    float xin[NIN];
    const float* xp = x + t * NIN;
#pragma unroll
    for (int k = 0; k < NIN; k++) xin[k] = xp[k];
    float ss = 0.f, sd = 0.f;
    float* hp = h0 + (size_t)t * HID;
#pragma unroll
    for (int o = 0; o < HID; o++) {
        float v = bias[o];
#pragma unroll
        for (int k = 0; k < NIN; k++) v += xin[k] * W[k * HID + o];
        v = elu1(v);
        hp[o] = v;
        hs[o][tid] = f2bf(v);
        ss += v * We[o];
        sd += v * We[HID + o];
    }
    ssrc[t] = exp2f(ss * NLOG2E);   // E_j = exp(-ss_j)
    sdst[t] = sd * NLOG2E;          // linear, consumer folds bias + exp2
    __syncthreads();
#pragma unroll
    for (int p = 0; p < 4; p++) {
        int row = p * 8 + (tid >> 5);
        int c = (tid & 31) * 8;
        short8 v8 = *(const short8*)&hs[row][c];
        *(short8*)(void*)&hTb[(size_t)(b * HID + row) * G + g0 + c] = v8;
    }
}

// Partial message-passing: grid 1024 = 256 gene-blocks x 4 j-quarters.
// 512 threads = 8 waves (b x jq0..3). Launch bounds (512,2): proven no-spill
// config (R9: VGPR 52). Staging: 4-deep batched float4 loads (4x outstanding
// vs R9 serial) then bit-pack. Inner loop: ex = D_i * E_j (one mul; exp2
// folded into producers) -> per-edge transcendentals halved. Partials to ws.
__global__ __launch_bounds__(512, 2) void k_mp(
    const float* __restrict__ adj, const float* __restrict__ ssrc,
    const float* __restrict__ sdst, const ushort_t* __restrict__ hTb_in,
    const float* __restrict__ bep, float coef, float* __restrict__ pr) {
    __shared__ __align__(16) float ssm[BSZ][1024];    // 8 KB (holds E_j)
    __shared__ __align__(16) uint_t abits[32][17];    // 2.2 KB
    __shared__ __align__(16) float red[6][64][9];     // 13.8 KB

    int tid = threadIdx.x;              // 0..511
    int gblk = blockIdx.x >> 2, jh = blockIdx.x & 3;
    int g0 = gblk * 16, j0 = jh * 1024;
    int l = tid & 63, w = tid >> 6;     // wave 0..7
    int b = w >> 2, jq = w & 3;
    int m = l & 15, kg = l >> 4;

    // hTb prefetch first (longest dependency to first MFMA)
    int jstart = j0 + jq * 256;
    const ushort_t* hb0 = hTb_in + (size_t)(b * HID + m) * G + jstart + kg * 8;
    const ushort_t* hb1 = hb0 + (size_t)16 * G;
    short8 pb0[2], pb1[2];
#pragma unroll
    for (int d = 0; d < 2; d++) {
        pb0[d] = *(const short8*)(const void*)(hb0 + d * 32);
        pb1[d] = *(const short8*)(const void*)(hb1 + d * 32);
    }

    // stage ssm quarter (E values): 1 float4/thread
    {
        int bb = tid >> 8, j4 = tid & 255;
        *(float4*)&ssm[bb][j4 * 4] = *(const float4*)&ssrc[bb * G + j0 + j4 * 4];
    }
    // stage adjacency bits: 2 passes x 4-deep batched loads, then pack
    {
        int r = tid >> 8, f4 = tid & 255;
        int word = f4 >> 3;
        int sh2 = (tid & 7) * 4;
        bool st = (tid & 7) == 0;
        float4 ld[4];
#pragma unroll
        for (int half = 0; half < 2; half++) {
#pragma unroll
            for (int q = 0; q < 4; q++)
                ld[q] = *(const float4*)&adj[(size_t)(g0 + (half * 4 + q) * 2 + r) * G +
                                             j0 + f4 * 4];
#pragma unroll
            for (int q = 0; q < 4; q++) {
                float4 v4 = ld[q];
                uint_t nib = (uint_t)(v4.x != 0.f) | ((uint_t)(v4.y != 0.f) << 1) |
                             ((uint_t)(v4.z != 0.f) << 2) | ((uint_t)(v4.w != 0.f) << 3);
                uint_t wd = nib << sh2;
                wd |= __shfl_xor(wd, 1);
                wd |= __shfl_xor(wd, 2);
                wd |= __shfl_xor(wd, 4);
                if (st) abits[word][(half * 4 + q) * 2 + r] = wd;
            }
        }
    }

    float Dv = exp2f(sdst[b * G + g0 + m] + bep[0] * NLOG2E);  // exp(-(sd_i+b_e))
    const float wm1 = 1.f - coef;
    floatx4 c0 = {0.f, 0.f, 0.f, 0.f}, c1 = {0.f, 0.f, 0.f, 0.f};
    float es = 0.f;
    __syncthreads();

    const float* svp = &ssm[b][jq * 256 + kg * 8];
    float4 sv0[2], sv1[2];
    uint_t bwr[2];
#pragma unroll
    for (int d = 0; d < 2; d++) {
        sv0[d] = *(const float4*)&svp[d * 32];
        sv1[d] = *(const float4*)&svp[d * 32 + 4];
        bwr[d] = abits[jq * 8 + d][m];
    }

#pragma unroll
    for (int jc = 0; jc < 8; jc++) {
        int lc = jc & 1;
        short8 bf0 = pb0[lc], bf1 = pb1[lc];
        float4 s0 = sv0[lc], s1 = sv1[lc];
        uint_t bw = bwr[lc];
        if (jc + 2 < 8) {
            pb0[lc] = *(const short8*)(const void*)(hb0 + (jc + 2) * 32);
            pb1[lc] = *(const short8*)(const void*)(hb1 + (jc + 2) * 32);
            sv0[lc] = *(const float4*)&svp[(jc + 2) * 32];
            sv1[lc] = *(const float4*)&svp[(jc + 2) * 32 + 4];
            bwr[lc] = abits[jq * 8 + jc + 2][m];
        }
        float ev[8] = {s0.x, s0.y, s0.z, s0.w, s1.x, s1.y, s1.z, s1.w};
        short8 af;
#pragma unroll
        for (int t8 = 0; t8 < 8; t8++) {
            float bitf = (float)((bw >> (kg * 8 + t8)) & 1u);
            float wgt = __builtin_fmaf(bitf, wm1, coef);  // bit?1:coef
            float ex = Dv * ev[t8];                       // = exp(-logit)
            float e = __builtin_amdgcn_rcpf(1.f + ex) * wgt;
            es += e;
            af[t8] = (short)(__float_as_uint(e) >> 16);   // bf16 by truncation
        }
        c0 = __builtin_amdgcn_mfma_f32_16x16x32_bf16(af, bf0, c0, 0, 0, 0);
        c1 = __builtin_amdgcn_mfma_f32_16x16x32_bf16(af, bf1, c1, 0, 0, 0);
    }

    // 4-way jq merge
    if (jq) {
        int widx = b * 3 + jq - 1;
#pragma unroll
        for (int r = 0; r < 4; r++) {
            red[widx][l][r] = c0[r];
            red[widx][l][4 + r] = c1[r];
        }
        red[widx][l][8] = es;
    }
    __syncthreads();
    if (!jq) {
#pragma unroll
        for (int q = 0; q < 3; q++) {
            int widx = b * 3 + q;
#pragma unroll
            for (int r = 0; r < 4; r++) {
                c0[r] += red[widx][l][r];
                c1[r] += red[widx][l][4 + r];
            }
            es += red[widx][l][8];
        }
        es += __shfl_xor(es, 16);
        es += __shfl_xor(es, 32);
        float* prb = pr + (size_t)blockIdx.x * 1056;
#pragma unroll
        for (int r = 0; r < 4; r++) {
            int gene = (l >> 4) * 4 + r;   // C/D: row=(l>>4)*4+reg, col=l&15
            int row = gene * 2 + b;
            prb[row * 32 + m] = c0[r];
            prb[row * 32 + 16 + m] = c1[r];
        }
        if (l < 16) prb[1024 + l * 2 + b] = es;
    }
}

// Combine 4 j-quarter partials + node/merge MLP (+BN+proj+hT for layer 1).
// Grid 256 x 1024 threads; post phase identical to the verified R0 tail.
template <bool DO_BN>
__global__ __launch_bounds__(1024, 4) void k_post(
    const float* __restrict__ pr, const float* __restrict__ hin,
    const float* __restrict__ Wn, const float* __restrict__ bnb,
    const float* __restrict__ Wm, const float* __restrict__ bmb,
    const float* __restrict__ gamma, const float* __restrict__ beta,
    const float* __restrict__ We2, float* __restrict__ outp,
    ushort_t* __restrict__ hTb_out, float* __restrict__ s2s,
    float* __restrict__ s2d) {
    __shared__ __align__(16) float rec[32][68];
    __shared__ __align__(16) float rec2[32][68];
    __shared__ __align__(16) ushort_t tb[BSZ][HID][16];
    __shared__ __align__(16) float Wns[2048];
    __shared__ __align__(16) float Wms[2048];

    int tid = threadIdx.x;
    int g0 = blockIdx.x * 16;
    if (tid < 512) {
        ((float4*)Wns)[tid] = ((const float4*)Wn)[tid];
    } else {
        ((float4*)Wms)[tid - 512] = ((const float4*)Wm)[tid - 512];
    }
    int rl = tid >> 5, hh = tid & 31;
    int gene = rl >> 1, bb = rl & 1;
    const float* p0 = pr + (size_t)blockIdx.x * 4 * 1056;
    float rv = p0[rl * 32 + hh] + p0[1056 + rl * 32 + hh] +
               p0[2112 + rl * 32 + hh] + p0[3168 + rl * 32 + hh];
    float esv = p0[1024 + rl] + p0[1056 + 1024 + rl] +
                p0[2112 + 1024 + rl] + p0[3168 + 1024 + rl];
    float xv = hin[((size_t)(bb * G + g0 + gene)) * HID + hh];
    rec[rl][hh] = rv;
    rec[rl][32 + hh] = xv * esv;
    __syncthreads();

    float v = bnb[hh];
#pragma unroll
    for (int k4 = 0; k4 < 16; k4++) {
        float4 r4 = *(const float4*)&rec[rl][k4 * 4];
        v += r4.x * Wns[(k4 * 4 + 0) * HID + hh];
        v += r4.y * Wns[(k4 * 4 + 1) * HID + hh];
        v += r4.z * Wns[(k4 * 4 + 2) * HID + hh];
        v += r4.w * Wns[(k4 * 4 + 3) * HID + hh];
    }
    v = elu1(v);
    rec2[rl][hh] = v;
    rec2[rl][32 + hh] = xv;
    // row handled by one half-wave: lockstep makes rec2 visible w/o barrier
    float u = bmb[hh];
#pragma unroll
    for (int k4 = 0; k4 < 16; k4++) {
        float4 r4 = *(const float4*)&rec2[rl][k4 * 4];
        u += r4.x * Wms[(k4 * 4 + 0) * HID + hh];
        u += r4.y * Wms[(k4 * 4 + 1) * HID + hh];
        u += r4.z * Wms[(k4 * 4 + 2) * HID + hh];
        u += r4.w * Wms[(k4 * 4 + 3) * HID + hh];
    }
    float h1v = elu1(u);
    if (!DO_BN) {
        outp[((size_t)(bb * G + g0 + gene)) * HID + hh] = h1v;
    } else {
        // wave holds gene's full 64 values (lanes 0-31: b=0, 32-63: b=1)
        float s = h1v, sq = h1v * h1v;
#pragma unroll
        for (int mm = 32; mm; mm >>= 1) {
            s += __shfl_xor(s, mm);
            sq += __shfl_xor(sq, mm);
        }
        float mu = s * (1.f / 64.f);
        float var = sq * (1.f / 64.f) - mu * mu;
        float rstd = rsqrtf(var + 1e-5f);
        float hn = (h1v - mu) * rstd * gamma[g0 + gene] + beta[g0 + gene];
        outp[((size_t)(bb * G + g0 + gene)) * HID + hh] = hn;
        tb[bb][hh][gene] = f2bf(hn);
        float ps = hn * We2[hh], pd = hn * We2[HID + hh];
#pragma unroll
        for (int mm = 16; mm; mm >>= 1) {
            ps += __shfl_xor(ps, mm);
            pd += __shfl_xor(pd, mm);
        }
        if (hh == 0) {
            s2s[bb * G + g0 + gene] = exp2f(ps * NLOG2E);  // E for layer 2
            s2d[bb * G + g0 + gene] = pd * NLOG2E;         // linear
        }
        __syncthreads();
        if (tid < 128) {
            int b2 = tid >> 6, c = (tid >> 1) & 31, half = tid & 1;
            short8 v8 = *(const short8*)&tb[b2][c][half * 8];
            *(short8*)(void*)&hTb_out[(size_t)(b2 * HID + c) * G + g0 + half * 8] = v8;
        }
    }
}

extern "C" void kernel_launch(void* const* d_in, const int* in_sizes, int n_in,
                              void* d_out, int out_size, void* d_ws, size_t ws_size,
                              hipStream_t stream) {
    const float* x      = (const float*)d_in[0];
    const float* edges1 = (const float*)d_in[1];
    const float* edges2 = (const float*)d_in[2];
    const float* W_inf  = (const float*)d_in[3];
    const float* b_inf  = (const float*)d_in[4];
    const float* W_e1   = (const float*)d_in[5];
    const float* b_e1   = (const float*)d_in[6];
    const float* W_e2   = (const float*)d_in[7];
    const float* b_e2   = (const float*)d_in[8];
    const float* W_n1   = (const float*)d_in[9];
    const float* b_n1   = (const float*)d_in[10];
    const float* W_n2   = (const float*)d_in[11];
    const float* b_n2   = (const float*)d_in[12];
    const float* W_m1   = (const float*)d_in[13];
    const float* b_m1   = (const float*)d_in[14];
    const float* W_m2   = (const float*)d_in[15];
    const float* b_m2   = (const float*)d_in[16];
    const float* bn_g   = (const float*)d_in[17];
    const float* bn_b   = (const float*)d_in[18];
    float* out = (float*)d_out;

    float* ws = (float*)d_ws;
    float* h0   = ws;                           // 262144 floats
    float* h1n  = ws + 262144;                  // 262144
    float* s1s  = ws + 524288;                  // 8192
    float* s1d  = ws + 532480;                  // 8192
    float* s2s  = ws + 540672;                  // 8192
    float* s2d  = ws + 548864;                  // 8192
    ushort_t* hTb  = (ushort_t*)(ws + 557056);  // 262144 ushorts = 131072 floats
    ushort_t* hTb2 = (ushort_t*)(ws + 688128);  // 262144 ushorts
    float* pr = ws + 819200;                    // 1024*1056 = 1081344 floats
    // total ~ 1900544 floats = 7.6 MB

    const float ALPHA = 0.005f, BETA = 5e-5f;

    k_setup1<<<32, 256, 0, stream>>>(x, W_inf, b_inf, W_e1, h0, hTb, s1s, s1d);
    k_mp<<<1024, 512, 0, stream>>>(edges1, s1s, s1d, hTb, b_e1, ALPHA, pr);
    k_post<true><<<256, 1024, 0, stream>>>(
        pr, h0, W_n1, b_n1, W_m1, b_m1, bn_g, bn_b, W_e2,
        h1n, hTb2, s2s, s2d);
    k_mp<<<1024, 512, 0, stream>>>(edges2, s2s, s2d, hTb2, b_e2, BETA, pr);
    k_post<false><<<256, 1024, 0, stream>>>(
        pr, h1n, W_n2, b_n2, W_m2, b_m2, nullptr, nullptr, nullptr,
        out, nullptr, nullptr, nullptr);
}